// Round 1
// baseline (1754.118 us; speedup 1.0000x reference)
//
#include <hip/hip_runtime.h>
#include <cmath>

#define B_PAT 400
#define N_ROWS 8000
#define DDIM 100
#define SCALER 4
#define BLOCKS_PER_B 5
#define WAVES_PER_B (BLOCKS_PER_B * 4)
#define TILES 125   /* 8000 / 64 rows per tile */

// One pass over x: per row compute dot(x,dim_weight) -> tanh -> alpha,
// dot(x,w[:,1]) -> beta, and accumulate alpha*x into pooled[b,:].
// Wave handles 2 rows per inner step: lanes 0..31 -> row 2u, lanes 32..63 -> row 2u+1.
// Lane covers d = (lane&31) + {0,32,64,96}; reduction is 5 shfl_xor levels within
// each 32-lane half. alpha/beta gathered into "row == lane" registers via one
// cross-half swap, stored coalesced once per 64-row tile.
__global__ __launch_bounds__(256) void pool_kernel(
    const float* __restrict__ x,
    const float* __restrict__ dim_weight,
    const float* __restrict__ w,
    float* __restrict__ alpha_out,
    float* __restrict__ beta_out,
    float* __restrict__ pooled)
{
    const int b    = blockIdx.x / BLOCKS_PER_B;
    const int sub  = blockIdx.x % BLOCKS_PER_B;
    const int lane = threadIdx.x & 63;
    const int wave = sub * 4 + (threadIdx.x >> 6);
    const int q    = lane & 31;   // within-row element offset base
    const int half = lane >> 5;   // which of the two rows this lane works on
    const bool q4   = (q < 4);               // d = 96..99 only
    const bool same = ((lane & 1) == half);  // row(lane) lives in own half?

    // per-lane loop-invariant weights
    const float c0 = dim_weight[q];
    const float c1 = dim_weight[q + 32];
    const float c2 = dim_weight[q + 64];
    const float c3 = q4 ? dim_weight[q + 96] : 0.f;
    const float w0 = w[q * 2 + 1];
    const float w1 = w[(q + 32) * 2 + 1];
    const float w2 = w[(q + 64) * 2 + 1];
    const float w3 = q4 ? w[(q + 96) * 2 + 1] : 0.f;

    float acc0 = 0.f, acc1 = 0.f, acc2 = 0.f, acc3 = 0.f;

    const size_t bbase = (size_t)b * N_ROWS;

    for (int t = wave; t < TILES; t += WAVES_PER_B) {
        const size_t rowbase = (bbase + (size_t)t * 64) * DDIM;
        const float* p0 = x + rowbase + half * DDIM + q;
        float asave = 0.f, bsave = 0.f;
        #pragma unroll 4
        for (int u = 0; u < 32; ++u) {
            const float* p = p0 + u * (2 * DDIM);
            float x0 = p[0];
            float x1 = p[32];
            float x2 = p[64];
            float x3 = q4 ? p[96] : 0.f;
            float s1 = fmaf(x0, c0, fmaf(x1, c1, fmaf(x2, c2, x3 * c3)));
            float s2 = fmaf(x0, w0, fmaf(x1, w1, fmaf(x2, w2, x3 * w3)));
            #pragma unroll
            for (int off = 16; off > 0; off >>= 1) {
                s1 += __shfl_xor(s1, off);
                s2 += __shfl_xor(s2, off);
            }
            float a = tanhf(s1);
            acc0 = fmaf(a, x0, acc0);
            acc1 = fmaf(a, x1, acc1);
            acc2 = fmaf(a, x2, acc2);
            acc3 = fmaf(a, x3, acc3);
            // gather alpha/beta of row (lane) into this lane's save regs
            float a_sw = __shfl_xor(a, 32);
            float b_sw = __shfl_xor(s2, 32);
            float a_pick = same ? a  : a_sw;
            float b_pick = same ? s2 : b_sw;
            if ((lane >> 1) == u) { asave = a_pick; bsave = b_pick; }
        }
        const size_t on = bbase + (size_t)t * 64 + lane;
        alpha_out[on] = asave;   // coalesced 256B store per tile
        beta_out[on]  = bsave;
    }

    // flush per-wave pooled partials (each d gets 2 adds/wave, 40 total per loc)
    float* pb = pooled + (size_t)b * DDIM;
    atomicAdd(pb + q,      acc0);
    atomicAdd(pb + q + 32, acc1);
    atomicAdd(pb + q + 64, acc2);
    if (q4) atomicAdd(pb + q + 96, acc3);
}

// out[b,:] = concat(pooled[b,:], x_scaler[b,:]) @ w   (104 x 2 GEMV per b)
__global__ __launch_bounds__(64) void head_kernel(
    const float* __restrict__ pooled,
    const float* __restrict__ x_scaler,
    const float* __restrict__ w,
    float* __restrict__ out)
{
    const int b = blockIdx.x;
    const int lane = threadIdx.x;
    float f0 = pooled[(size_t)b * DDIM + lane];   // lane < 64 < 100
    const float wa0 = w[lane * 2];
    const float wb0 = w[lane * 2 + 1];
    int i1 = lane + 64;
    float f1 = 0.f, wa1 = 0.f, wb1 = 0.f;
    if (i1 < DDIM + SCALER) {
        f1  = (i1 < DDIM) ? pooled[(size_t)b * DDIM + i1]
                          : x_scaler[b * SCALER + (i1 - DDIM)];
        wa1 = w[i1 * 2];
        wb1 = w[i1 * 2 + 1];
    }
    float o0 = fmaf(f0, wa0, f1 * wa1);
    float o1 = fmaf(f0, wb0, f1 * wb1);
    #pragma unroll
    for (int off = 32; off > 0; off >>= 1) {
        o0 += __shfl_xor(o0, off);
        o1 += __shfl_xor(o1, off);
    }
    if (lane == 0) {
        out[b * 2]     = o0;
        out[b * 2 + 1] = o1;
    }
}

extern "C" void kernel_launch(void* const* d_in, const int* in_sizes, int n_in,
                              void* d_out, int out_size, void* d_ws, size_t ws_size,
                              hipStream_t stream)
{
    const float* x  = (const float*)d_in[0];
    const float* xs = (const float*)d_in[1];
    const float* dw = (const float*)d_in[2];
    const float* w  = (const float*)d_in[3];

    float* out    = (float*)d_out;                    // [400,2]
    float* alpha  = out + B_PAT * 2;                  // [400,1,8000]
    float* beta   = alpha + (size_t)B_PAT * N_ROWS;   // [400,8000]
    float* pooled = (float*)d_ws;                     // [400,100] scratch

    hipMemsetAsync(pooled, 0, B_PAT * DDIM * sizeof(float), stream);
    pool_kernel<<<B_PAT * BLOCKS_PER_B, 256, 0, stream>>>(x, dw, w, alpha, beta, pooled);
    head_kernel<<<B_PAT, 64, 0, stream>>>(pooled, xs, w, out);
}